// Round 5
// baseline (896.886 us; speedup 1.0000x reference)
//
#include <hip/hip_runtime.h>
#include <hip/hip_bf16.h>

typedef __hip_bfloat16 bf16;
__device__ __forceinline__ float bf2f(bf16 v) { return __bfloat162float(v); }

typedef __attribute__((ext_vector_type(8))) short short8;
typedef __attribute__((ext_vector_type(4))) float floatx4;

#define EB_BITS 8            // 256 edge segments per coarse bucket
#define VB_BITS 10           // 1024 vertex segments per coarse bucket
#define MAXBK   256          // coarse bucket ceiling (79+98=177 here)
#define F1_ITEMS 1024        // incidences per bucketize block
#define EFB 8                // blocks per e-bucket  -> 32 edges/block,  8KB acc
#define VFB 8                // blocks per v-bucket  -> 128 verts/block, 32KB acc
#define XS_STRIDE 136        // ushort; gemm LDS row stride

__device__ __forceinline__ int rbase(int b, int nEB, int capE, int capV) {
  return (b < nEB) ? b * capE : nEB * capE + (b - nEB) * capV;
}

// ===========================================================================
// Init per-bucket write cursors to region bases.
// ===========================================================================
__global__ void init_cursor_kernel(int* __restrict__ gcursor, int KB,
                                   int nEB, int capE, int capV) {
  const int b = threadIdx.x;
  if (b < KB) gcursor[b] = rbase(b, nEB, capE, capV);
}

// ===========================================================================
// Bucketize body (round-1 proven): partition incidences into 177 coarse
// bucket regions with dense writes. Record formats:
//   E-side: (e_local:8  << 17) | v   (v  <= 17 bits)
//   V-side: (v_local:10 << 17) | e   (e  <= 17 bits)
// LDS carved from the shared 17.4KB buffer (13.3KB used).
// ===========================================================================
__device__ void bucketize_body(int* smem4,
    const int* __restrict__ vertex, const int* __restrict__ edges,
    int* __restrict__ gcursor, int* __restrict__ records,
    int nnz, int KB, int nEB, int bb) {
  int* cnt    = smem4;            // 256
  int* scanEx = smem4 + 256;      // 256
  int* bases  = smem4 + 512;      // 256
  int* wsum4  = smem4 + 768;      // 4
  int* staged = smem4 + 772;      // 2048
  unsigned char* sbkt = (unsigned char*)(smem4 + 772 + 2048);  // 2048 B

  const int tid  = threadIdx.x;
  const int lane = tid & 63;
  const int wid  = tid >> 6;
  const int base = bb * F1_ITEMS;
  const int iEnd = min(nnz, base + F1_ITEMS);

  cnt[tid] = 0;
  __syncthreads();

  int recs[8];
  int bks[8];
  int nmy = 0;
#pragma unroll
  for (int j = 0; j < 4; ++j) {
    const int i = base + tid + j * 256;
    if (i < iEnd) {
      const int e = __builtin_nontemporal_load(&edges[i]);
      const int v = __builtin_nontemporal_load(&vertex[i]);
      const int bkE = e >> EB_BITS;
      recs[nmy] = ((e & ((1 << EB_BITS) - 1)) << 17) | v;  bks[nmy] = bkE;  ++nmy;
      const int bkV = nEB + (v >> VB_BITS);
      recs[nmy] = ((v & ((1 << VB_BITS) - 1)) << 17) | e;  bks[nmy] = bkV;  ++nmy;
      atomicAdd(&cnt[bkE], 1);
      atomicAdd(&cnt[bkV], 1);
    }
  }
  __syncthreads();

  // Exclusive scan over 256 buckets: shfl wave-scan + 4-way cross-wave
  const int c = cnt[tid];
  int inc = c;
#pragma unroll
  for (int d = 1; d < 64; d <<= 1) {
    int t = __shfl_up(inc, d, 64);
    if (lane >= d) inc += t;
  }
  if (lane == 63) wsum4[wid] = inc;
  __syncthreads();
  if (tid < 4) {
    int wv = wsum4[tid];
#pragma unroll
    for (int d = 1; d < 4; d <<= 1) {
      int t = __shfl_up(wv, d, 64);
      if (tid >= d) wv += t;
    }
    wsum4[tid] = wv;
  }
  __syncthreads();
  const int excl = inc - c + (wid > 0 ? wsum4[wid - 1] : 0);

  if (tid < KB && c > 0) bases[tid] = atomicAdd(&gcursor[tid], c);
  scanEx[tid] = excl;
  __syncthreads();
  cnt[tid] = 0;
  __syncthreads();

  for (int r = 0; r < nmy; ++r) {
    const int b = bks[r];
    const int p = atomicAdd(&cnt[b], 1);
    const int s = scanEx[b] + p;
    staged[s] = recs[r];
    sbkt[s] = (unsigned char)b;
  }
  __syncthreads();

  const int nrec = 2 * (iEnd - base);
  for (int s = tid; s < nrec; s += 256) {
    const int b = sbkt[s];
    records[bases[b] + (s - scanEx[b])] = staged[s];
  }
}

// ===========================================================================
// GEMM body: Xl[N,64](bf16) = X[N,128] @ W[128,64]. 4 waves, 64-row tiles,
// mfma_f32_16x16x32_bf16. LDS buffer reused: Ws first (bfrags hoisted),
// then Xs per tile. (verified layouts, learn_hip m89/m120)
// ===========================================================================
__device__ __forceinline__ unsigned int pack_bf16x2(float lo, float hi) {
  bf16 a = __float2bfloat16(lo);
  bf16 b = __float2bfloat16(hi);
  unsigned short ua = *(unsigned short*)&a;
  unsigned short ub = *(unsigned short*)&b;
  return (unsigned int)ua | ((unsigned int)ub << 16);
}

__device__ void gemm_body(int* smem4,
    const float* __restrict__ X, const float* __restrict__ W,
    bf16* __restrict__ Xl, int Nrows, int ntiles, int gb, int GB) {
  unsigned short* S = (unsigned short*)smem4;   // Ws, then Xs (17.4 KB)

  const int tid  = threadIdx.x;
  const int wave = tid >> 6;
  const int lane = tid & 63;
  const int quad = lane >> 4;
  const int l15  = lane & 15;

  // Stage W^T into S
  for (int i = tid; i < 8192; i += 256) {
    const int k = i >> 6, n = i & 63;
    bf16 h = __float2bfloat16(W[i]);
    S[n * XS_STRIDE + k] = *(unsigned short*)&h;
  }
  __syncthreads();

  short8 bfrag[4][4];
#pragma unroll
  for (int ct = 0; ct < 4; ++ct)
#pragma unroll
    for (int kt = 0; kt < 4; ++kt)
      bfrag[ct][kt] = *(const short8*)&S[(ct * 16 + l15) * XS_STRIDE + kt * 32 + quad * 8];
  __syncthreads();   // done with Ws; S becomes Xs

  const int r  = tid >> 2;
  const int c0 = (tid & 3) * 32;

  for (int tile = gb; tile < ntiles; tile += GB) {
    const int row0 = tile * 64;
    {
      int rr = row0 + r;
      if (rr >= Nrows) rr = Nrows - 1;
      const float* src = X + (size_t)rr * 128 + c0;
      unsigned short* dst = &S[r * XS_STRIDE + c0];
#pragma unroll
      for (int q = 0; q < 4; ++q) {
        const float4 f0 = *(const float4*)(src + q * 8);
        const float4 f1 = *(const float4*)(src + q * 8 + 4);
        uint4 o;
        o.x = pack_bf16x2(f0.x, f0.y);
        o.y = pack_bf16x2(f0.z, f0.w);
        o.z = pack_bf16x2(f1.x, f1.y);
        o.w = pack_bf16x2(f1.z, f1.w);
        *(uint4*)(dst + q * 8) = o;
      }
    }
    __syncthreads();

    const int m = wave * 16 + l15;
    short8 afrag[4];
#pragma unroll
    for (int kt = 0; kt < 4; ++kt)
      afrag[kt] = *(const short8*)&S[m * XS_STRIDE + kt * 32 + quad * 8];

    floatx4 acc[4];
#pragma unroll
    for (int ct = 0; ct < 4; ++ct) {
      acc[ct] = (floatx4){0.f, 0.f, 0.f, 0.f};
#pragma unroll
      for (int kt = 0; kt < 4; ++kt)
        acc[ct] = __builtin_amdgcn_mfma_f32_16x16x32_bf16(
            afrag[kt], bfrag[ct][kt], acc[ct], 0, 0, 0);
    }

    const int rbase_ = row0 + wave * 16 + quad * 4;
#pragma unroll
    for (int ct = 0; ct < 4; ++ct) {
      const int col = ct * 16 + l15;
#pragma unroll
      for (int reg = 0; reg < 4; ++reg) {
        const int row = rbase_ + reg;
        if (row < Nrows) Xl[(size_t)row * 64 + col] = __float2bfloat16(acc[ct][reg]);
      }
    }
    __syncthreads();
  }
}

// ===========================================================================
// K1: bucketize blocks and gemm blocks co-scheduled in one launch
// (independent work; blockIdx branch; uniform per block so barriers are safe).
// ===========================================================================
__global__ __launch_bounds__(256) void fused1_kernel(
    const int* __restrict__ vertex, const int* __restrict__ edges,
    int* __restrict__ gcursor, int* __restrict__ records,
    const float* __restrict__ X, const float* __restrict__ W,
    bf16* __restrict__ Xl,
    int nnz, int KB, int nEB, int f1blocks, int Nrows, int ntiles, int GB) {
  __shared__ int smem4[4352];   // 17.4 KB, overlaid by both bodies
  if ((int)blockIdx.x < f1blocks)
    bucketize_body(smem4, vertex, edges, gcursor, records, nnz, KB, nEB, blockIdx.x);
  else
    gemm_body(smem4, X, W, Xl, Nrows, ntiles, blockIdx.x - f1blocks, GB);
}

// ===========================================================================
// K2: fused edge-side segment-sum. Block = (bucket b, slice q of EFB).
// Owns 32 edges -> acc[32][64] f32 in LDS (8KB). Scans the bucket's records,
// ballot-compacts matching ones, gathers Xl rows, LDS-atomicAdd (bank-free:
// addr = k*64+lane -> bank = lane&31, 2-way = free). Dense Xe writeback.
// ===========================================================================
__global__ __launch_bounds__(256) void efused_kernel(
    const bf16* __restrict__ Xl, const int* __restrict__ records,
    const int* __restrict__ gcursor, const float* __restrict__ degE,
    const float* __restrict__ W_edge, bf16* __restrict__ Xe,
    int E, int nEB, int capE) {
  __shared__ float acc[32 * 64];   // 8 KB
  __shared__ int stash[4][64];
  const int b    = blockIdx.x >> 3;      // EFB=8
  const int q    = blockIdx.x & 7;
  const int tid  = threadIdx.x;
  const int lane = tid & 63;
  const int wid  = tid >> 6;

  for (int i = tid; i < 32 * 64; i += 256) acc[i] = 0.f;
  __syncthreads();

  const int rbeg = b * capE;
  const int rend = gcursor[b];

  for (int cb = rbeg + wid * 64; cb < rend; cb += 256) {
    const int r = cb + lane;
    int m = 0, pk = 0;
    if (r < rend) {
      const int rec = records[r];
      const int el  = rec >> 17;          // 0..255
      if ((el >> 5) == q) { m = 1; pk = ((el & 31) << 17) | (rec & 0x1FFFF); }
    }
    const unsigned long long mask = __ballot(m);
    const int cntm = __popcll(mask);
    if (m) stash[wid][__popcll(mask & ((1ull << lane) - 1))] = pk;
    int j = 0;
    for (; j + 2 <= cntm; j += 2) {
      const int t0 = stash[wid][j], t1 = stash[wid][j + 1];
      const float f0 = bf2f(Xl[(size_t)(t0 & 0x1FFFF) * 64 + lane]);
      const float f1 = bf2f(Xl[(size_t)(t1 & 0x1FFFF) * 64 + lane]);
      atomicAdd(&acc[(t0 >> 17) * 64 + lane], f0);
      atomicAdd(&acc[(t1 >> 17) * 64 + lane], f1);
    }
    for (; j < cntm; ++j) {
      const int t = stash[wid][j];
      atomicAdd(&acc[(t >> 17) * 64 + lane], bf2f(Xl[(size_t)(t & 0x1FFFF) * 64 + lane]));
    }
  }
  __syncthreads();

  const int e0 = (b << EB_BITS) + (q << 5);
  for (int k = wid; k < 32; k += 4) {
    const int e = e0 + k;
    if (e < E) {
      const float s = degE[e] * W_edge[e];
      Xe[(size_t)e * 64 + lane] = __float2bfloat16(acc[k * 64 + lane] * s);
    }
  }
}

// ===========================================================================
// K3: fused vertex-side segment-sum. Block = (bucket b, slice s of VFB).
// Owns 128 vertices -> acc[128][64] f32 (32KB). out = acc * degV, dense.
// ===========================================================================
__global__ __launch_bounds__(256) void vfused_kernel(
    const bf16* __restrict__ Xe, const int* __restrict__ records,
    const int* __restrict__ gcursor, const float* __restrict__ degV,
    float* __restrict__ out, int N, int nEB, int capE, int capV) {
  __shared__ float acc[128 * 64];   // 32 KB
  __shared__ int stash[4][64];
  const int b    = blockIdx.x >> 3;      // VFB=8
  const int s    = blockIdx.x & 7;
  const int tid  = threadIdx.x;
  const int lane = tid & 63;
  const int wid  = tid >> 6;

  for (int i = tid; i < 128 * 64; i += 256) acc[i] = 0.f;
  __syncthreads();

  const int rbeg = nEB * capE + b * capV;
  const int rend = gcursor[nEB + b];

  for (int cb = rbeg + wid * 64; cb < rend; cb += 256) {
    const int r = cb + lane;
    int m = 0, pk = 0;
    if (r < rend) {
      const int rec = records[r];
      const int vl  = rec >> 17;          // 0..1023
      if ((vl >> 7) == s) { m = 1; pk = ((vl & 127) << 17) | (rec & 0x1FFFF); }
    }
    const unsigned long long mask = __ballot(m);
    const int cntm = __popcll(mask);
    if (m) stash[wid][__popcll(mask & ((1ull << lane) - 1))] = pk;
    int j = 0;
    for (; j + 2 <= cntm; j += 2) {
      const int t0 = stash[wid][j], t1 = stash[wid][j + 1];
      const float f0 = bf2f(Xe[(size_t)(t0 & 0x1FFFF) * 64 + lane]);
      const float f1 = bf2f(Xe[(size_t)(t1 & 0x1FFFF) * 64 + lane]);
      atomicAdd(&acc[(t0 >> 17) * 64 + lane], f0);
      atomicAdd(&acc[(t1 >> 17) * 64 + lane], f1);
    }
    for (; j < cntm; ++j) {
      const int t = stash[wid][j];
      atomicAdd(&acc[(t >> 17) * 64 + lane], bf2f(Xe[(size_t)(t & 0x1FFFF) * 64 + lane]));
    }
  }
  __syncthreads();

  const int v0 = (b << VB_BITS) + (s << 7);
  for (int k = wid; k < 128; k += 4) {
    const int v = v0 + k;
    if (v < N)
      __builtin_nontemporal_store(acc[k * 64 + lane] * degV[v], &out[(size_t)v * 64 + lane]);
  }
}

// ===========================================================================
extern "C" void kernel_launch(void* const* d_in, const int* in_sizes, int n_in,
                              void* d_out, int out_size, void* d_ws, size_t ws_size,
                              hipStream_t stream) {
  const float* X      = (const float*)d_in[0];
  const int*   vertex = (const int*)d_in[1];
  const int*   edges  = (const int*)d_in[2];
  const float* W      = (const float*)d_in[3];
  const float* degE   = (const float*)d_in[4];
  const float* degV   = (const float*)d_in[5];
  const float* W_edge = (const float*)d_in[6];
  float* out = (float*)d_out;

  const int nnz = in_sizes[1];
  const int E   = in_sizes[4];
  const int N   = in_sizes[5];

  const int nEB = (E + (1 << EB_BITS) - 1) >> EB_BITS;
  const int nVB = (N + (1 << VB_BITS) - 1) >> VB_BITS;
  const int KB  = nEB + nVB;

  const int capE = (nnz / nEB) * 3 / 2 + 256;
  const int capV = (nnz / nVB) * 3 / 2 + 256;
  const size_t rec_total = (size_t)nEB * capE + (size_t)nVB * capV;

  char* p = (char*)d_ws;
  auto alloc = [&](size_t bytes) -> void* {
    void* r = (void*)p;
    p += (bytes + 255) & ~(size_t)255;
    return r;
  };
  int*  gcursor = (int*)alloc(MAXBK * 4);
  int*  records = (int*)alloc(rec_total * 4);        // ~12.2 MB (live with Xl)
  bf16* Xl      = (bf16*)alloc((size_t)N * 64 * 2);  // 12.8 MB
  bf16* Xe      = (bf16*)alloc((size_t)E * 64 * 2);  //  2.56 MB

  const int f1blocks = (nnz + F1_ITEMS - 1) / F1_ITEMS;
  const int ntiles   = (N + 63) / 64;
  const int GB       = ntiles < 512 ? ntiles : 512;

  init_cursor_kernel<<<1, MAXBK, 0, stream>>>(gcursor, KB, nEB, capE, capV);
  fused1_kernel<<<f1blocks + GB, 256, 0, stream>>>(
      vertex, edges, gcursor, records, X, W, Xl,
      nnz, KB, nEB, f1blocks, N, ntiles, GB);
  efused_kernel<<<nEB * EFB, 256, 0, stream>>>(Xl, records, gcursor, degE, W_edge, Xe, E, nEB, capE);
  vfused_kernel<<<nVB * VFB, 256, 0, stream>>>(Xe, records, gcursor, degV, out, N, nEB, capE, capV);
}

// Round 6
// 200.873 us; speedup vs baseline: 4.4649x; 4.4649x over previous
//
#include <hip/hip_runtime.h>
#include <hip/hip_bf16.h>

typedef __hip_bfloat16 bf16;
__device__ __forceinline__ float bf2f(bf16 v) { return __bfloat162float(v); }

typedef __attribute__((ext_vector_type(8))) short short8;
typedef __attribute__((ext_vector_type(4))) float floatx4;

#define EB_BITS 8            // 256 edge segments per coarse bucket
#define VB_BITS 10           // 1024 vertex segments per coarse bucket
#define MAXBK   256          // coarse bucket ceiling (79+98=177 here)
#define F1_ITEMS 1024        // incidences per bucketize block
#define XS_STRIDE 136        // ushort; gemm LDS row stride
#define SCAN_CHUNK 1024

__device__ __forceinline__ int rbase(int b, int nEB, int capE, int capV) {
  return (b < nEB) ? b * capE : nEB * capE + (b - nEB) * capV;
}

// ===========================================================================
// Init per-bucket write cursors to region bases.
// ===========================================================================
__global__ void init_cursor_kernel(int* __restrict__ gcursor, int KB,
                                   int nEB, int capE, int capV) {
  const int b = threadIdx.x;
  if (b < KB) gcursor[b] = rbase(b, nEB, capE, capV);
}

// ===========================================================================
// Bucketize body (round-1 proven) + INLINE per-segment histogram:
// fire-and-forget global atomics into seghist[M] (480KB, L2-resident;
// this pattern == round-2 hist_kernel, which was cheap). Replaces the
// separate bucket_hist kernel (which re-read all records).
// Record formats:
//   E-side: (e_local:8  << 17) | v
//   V-side: (v_local:10 << 17) | e
// ===========================================================================
__device__ void bucketize_body(int* smem4,
    const int* __restrict__ vertex, const int* __restrict__ edges,
    int* __restrict__ gcursor, int* __restrict__ records,
    int* __restrict__ seghist,
    int nnz, int E, int KB, int nEB, int bb) {
  int* cnt    = smem4;            // 256
  int* scanEx = smem4 + 256;      // 256
  int* bases  = smem4 + 512;      // 256
  int* wsum4  = smem4 + 768;      // 4
  int* staged = smem4 + 772;      // 2048
  unsigned char* sbkt = (unsigned char*)(smem4 + 772 + 2048);  // 2048 B

  const int tid  = threadIdx.x;
  const int lane = tid & 63;
  const int wid  = tid >> 6;
  const int base = bb * F1_ITEMS;
  const int iEnd = min(nnz, base + F1_ITEMS);

  cnt[tid] = 0;
  __syncthreads();

  int recs[8];
  int bks[8];
  int nmy = 0;
#pragma unroll
  for (int j = 0; j < 4; ++j) {
    const int i = base + tid + j * 256;
    if (i < iEnd) {
      const int e = __builtin_nontemporal_load(&edges[i]);
      const int v = __builtin_nontemporal_load(&vertex[i]);
      const int bkE = e >> EB_BITS;
      recs[nmy] = ((e & ((1 << EB_BITS) - 1)) << 17) | v;  bks[nmy] = bkE;  ++nmy;
      const int bkV = nEB + (v >> VB_BITS);
      recs[nmy] = ((v & ((1 << VB_BITS) - 1)) << 17) | e;  bks[nmy] = bkV;  ++nmy;
      atomicAdd(&cnt[bkE], 1);
      atomicAdd(&cnt[bkV], 1);
      atomicAdd(&seghist[e], 1);       // global seg hist (no return -> pipelined)
      atomicAdd(&seghist[E + v], 1);
    }
  }
  __syncthreads();

  // Exclusive scan over 256 buckets: shfl wave-scan + 4-way cross-wave
  const int c = cnt[tid];
  int inc = c;
#pragma unroll
  for (int d = 1; d < 64; d <<= 1) {
    int t = __shfl_up(inc, d, 64);
    if (lane >= d) inc += t;
  }
  if (lane == 63) wsum4[wid] = inc;
  __syncthreads();
  if (tid < 4) {
    int wv = wsum4[tid];
#pragma unroll
    for (int d = 1; d < 4; d <<= 1) {
      int t = __shfl_up(wv, d, 64);
      if (tid >= d) wv += t;
    }
    wsum4[tid] = wv;
  }
  __syncthreads();
  const int excl = inc - c + (wid > 0 ? wsum4[wid - 1] : 0);

  if (tid < KB && c > 0) bases[tid] = atomicAdd(&gcursor[tid], c);
  scanEx[tid] = excl;
  __syncthreads();
  cnt[tid] = 0;
  __syncthreads();

  for (int r = 0; r < nmy; ++r) {
    const int b = bks[r];
    const int p = atomicAdd(&cnt[b], 1);
    const int s = scanEx[b] + p;
    staged[s] = recs[r];
    sbkt[s] = (unsigned char)b;
  }
  __syncthreads();

  const int nrec = 2 * (iEnd - base);
  for (int s = tid; s < nrec; s += 256) {
    const int b = sbkt[s];
    records[bases[b] + (s - scanEx[b])] = staged[s];
  }
}

// ===========================================================================
// GEMM body: Xl[N,64](bf16) = X[N,128] @ W[128,64]. 4 waves, 64-row tiles,
// mfma_f32_16x16x32_bf16. LDS reused: Ws first (bfrags hoisted), then Xs.
// (round-5 proven; verified layouts learn_hip m89/m120)
// ===========================================================================
__device__ __forceinline__ unsigned int pack_bf16x2(float lo, float hi) {
  bf16 a = __float2bfloat16(lo);
  bf16 b = __float2bfloat16(hi);
  unsigned short ua = *(unsigned short*)&a;
  unsigned short ub = *(unsigned short*)&b;
  return (unsigned int)ua | ((unsigned int)ub << 16);
}

__device__ void gemm_body(int* smem4,
    const float* __restrict__ X, const float* __restrict__ W,
    bf16* __restrict__ Xl, int Nrows, int ntiles, int gb, int GB) {
  unsigned short* S = (unsigned short*)smem4;   // Ws, then Xs (17.4 KB)

  const int tid  = threadIdx.x;
  const int wave = tid >> 6;
  const int lane = tid & 63;
  const int quad = lane >> 4;
  const int l15  = lane & 15;

  for (int i = tid; i < 8192; i += 256) {
    const int k = i >> 6, n = i & 63;
    bf16 h = __float2bfloat16(W[i]);
    S[n * XS_STRIDE + k] = *(unsigned short*)&h;
  }
  __syncthreads();

  short8 bfrag[4][4];
#pragma unroll
  for (int ct = 0; ct < 4; ++ct)
#pragma unroll
    for (int kt = 0; kt < 4; ++kt)
      bfrag[ct][kt] = *(const short8*)&S[(ct * 16 + l15) * XS_STRIDE + kt * 32 + quad * 8];
  __syncthreads();   // done with Ws; S becomes Xs

  const int r  = tid >> 2;
  const int c0 = (tid & 3) * 32;

  for (int tile = gb; tile < ntiles; tile += GB) {
    const int row0 = tile * 64;
    {
      int rr = row0 + r;
      if (rr >= Nrows) rr = Nrows - 1;
      const float* src = X + (size_t)rr * 128 + c0;
      unsigned short* dst = &S[r * XS_STRIDE + c0];
#pragma unroll
      for (int q = 0; q < 4; ++q) {
        const float4 f0 = *(const float4*)(src + q * 8);
        const float4 f1 = *(const float4*)(src + q * 8 + 4);
        uint4 o;
        o.x = pack_bf16x2(f0.x, f0.y);
        o.y = pack_bf16x2(f0.z, f0.w);
        o.z = pack_bf16x2(f1.x, f1.y);
        o.w = pack_bf16x2(f1.z, f1.w);
        *(uint4*)(dst + q * 8) = o;
      }
    }
    __syncthreads();

    const int m = wave * 16 + l15;
    short8 afrag[4];
#pragma unroll
    for (int kt = 0; kt < 4; ++kt)
      afrag[kt] = *(const short8*)&S[m * XS_STRIDE + kt * 32 + quad * 8];

    floatx4 acc[4];
#pragma unroll
    for (int ct = 0; ct < 4; ++ct) {
      acc[ct] = (floatx4){0.f, 0.f, 0.f, 0.f};
#pragma unroll
      for (int kt = 0; kt < 4; ++kt)
        acc[ct] = __builtin_amdgcn_mfma_f32_16x16x32_bf16(
            afrag[kt], bfrag[ct][kt], acc[ct], 0, 0, 0);
    }

    const int rbase_ = row0 + wave * 16 + quad * 4;
#pragma unroll
    for (int ct = 0; ct < 4; ++ct) {
      const int col = ct * 16 + l15;
#pragma unroll
      for (int reg = 0; reg < 4; ++reg) {
        const int row = rbase_ + reg;
        if (row < Nrows) Xl[(size_t)row * 64 + col] = __float2bfloat16(acc[ct][reg]);
      }
    }
    __syncthreads();
  }
}

// ===========================================================================
// K1: bucketize blocks and gemm blocks co-scheduled (round-5 proven branch).
// NOTE: records and Xl are live simultaneously here -> no aliasing.
// ===========================================================================
__global__ __launch_bounds__(256) void fused1_kernel(
    const int* __restrict__ vertex, const int* __restrict__ edges,
    int* __restrict__ gcursor, int* __restrict__ records,
    int* __restrict__ seghist,
    const float* __restrict__ X, const float* __restrict__ W,
    bf16* __restrict__ Xl,
    int nnz, int E, int KB, int nEB, int f1blocks, int Nrows, int ntiles, int GB) {
  __shared__ int smem4[4352];   // 17.4 KB, overlaid by both bodies
  if ((int)blockIdx.x < f1blocks)
    bucketize_body(smem4, vertex, edges, gcursor, records, seghist,
                   nnz, E, KB, nEB, blockIdx.x);
  else
    gemm_body(smem4, X, W, Xl, Nrows, ntiles, blockIdx.x - f1blocks, GB);
}

// ===========================================================================
// 3-kernel exclusive scan of seghist[0..M) -> offs (in place, round-2 proven)
// ===========================================================================
__global__ __launch_bounds__(256) void scan_part_kernel(
    int* __restrict__ cnt, int* __restrict__ psum, int M) {
  __shared__ int ws[4];
  const int tid  = threadIdx.x;
  const int lane = tid & 63;
  const int wid  = tid >> 6;
  const int base = blockIdx.x * SCAN_CHUNK + tid * 4;

  int c0 = 0, c1 = 0, c2 = 0, c3 = 0;
  if (base + 3 < M) {
    const int4 c = *(const int4*)&cnt[base];
    c0 = c.x; c1 = c.y; c2 = c.z; c3 = c.w;
  } else {
    if (base     < M) c0 = cnt[base];
    if (base + 1 < M) c1 = cnt[base + 1];
    if (base + 2 < M) c2 = cnt[base + 2];
    if (base + 3 < M) c3 = cnt[base + 3];
  }
  const int s = c0 + c1 + c2 + c3;
  int inc = s;
#pragma unroll
  for (int d = 1; d < 64; d <<= 1) {
    const int t = __shfl_up(inc, d, 64);
    if (lane >= d) inc += t;
  }
  if (lane == 63) ws[wid] = inc;
  __syncthreads();
  int wbase = 0;
  for (int w = 0; w < wid; ++w) wbase += ws[w];
  const int excl = wbase + inc - s;

  if (base + 3 < M) {
    int4 o;
    o.x = excl; o.y = excl + c0; o.z = excl + c0 + c1; o.w = excl + c0 + c1 + c2;
    *(int4*)&cnt[base] = o;
  } else {
    if (base     < M) cnt[base]     = excl;
    if (base + 1 < M) cnt[base + 1] = excl + c0;
    if (base + 2 < M) cnt[base + 2] = excl + c0 + c1;
    if (base + 3 < M) cnt[base + 3] = excl + c0 + c1 + c2;
  }
  if (tid == 255) psum[blockIdx.x] = wbase + inc;
}

__global__ __launch_bounds__(256) void scan_top_kernel(
    const int* __restrict__ psum, int* __restrict__ pbase,
    int* __restrict__ cnt, int nP, int M) {
  __shared__ int ws[4];
  const int tid  = threadIdx.x;
  const int lane = tid & 63;
  const int wid  = tid >> 6;
  const int v = (tid < nP) ? psum[tid] : 0;
  int inc = v;
#pragma unroll
  for (int d = 1; d < 64; d <<= 1) {
    const int t = __shfl_up(inc, d, 64);
    if (lane >= d) inc += t;
  }
  if (lane == 63) ws[wid] = inc;
  __syncthreads();
  int wbase = 0;
  for (int w = 0; w < wid; ++w) wbase += ws[w];
  const int excl = wbase + inc - v;
  if (tid < nP) pbase[tid] = excl;
  if (tid == 255) cnt[M] = wbase + inc;   // sentinel = 2*nnz
}

__global__ __launch_bounds__(256) void scan_apply_kernel(
    int* __restrict__ cnt, const int* __restrict__ pbase, int M) {
  const int base = blockIdx.x * SCAN_CHUNK + threadIdx.x * 4;
  const int add  = pbase[blockIdx.x];
  if (base + 3 < M) {
    int4 c = *(const int4*)&cnt[base];
    c.x += add; c.y += add; c.z += add; c.w += add;
    *(int4*)&cnt[base] = c;
  } else {
    for (int j = 0; j < 4; ++j)
      if (base + j < M) cnt[base + j] += add;
  }
}

// ===========================================================================
// Fill: per-bucket LDS cursors (init from global offs), dense perm window
// writes (single-writer per bucket -> L2 write-merging; round-1 proven).
// ===========================================================================
__global__ __launch_bounds__(1024) void fill_bucket_kernel(
    const int* __restrict__ records, const int* __restrict__ gcursor,
    const int* __restrict__ offs, int* __restrict__ perm,
    int nEB, int capE, int capV, int E, int M) {
  __shared__ int cursors[1 << VB_BITS];
  const int b   = blockIdx.x;
  const int tid = threadIdx.x;

  const int base = rbase(b, nEB, capE, capV);
  const int end  = gcursor[b];

  int seg_lo, segN;
  if (b < nEB) { seg_lo = b << EB_BITS;               segN = min(E - seg_lo, 1 << EB_BITS); }
  else         { seg_lo = E + ((b - nEB) << VB_BITS); segN = min(M - seg_lo, 1 << VB_BITS); }

  if (tid < segN) cursors[tid] = offs[seg_lo + tid];
  __syncthreads();

  for (int r = base + tid; r < end; r += 1024) {
    const int rec = records[r];
    const int p = atomicAdd(&cursors[rec >> 17], 1);
    perm[p] = rec & 0x1FFFF;
  }
}

// ===========================================================================
// Gather 1: one wave per hyperedge. Xe[e] = degE[e]*W_edge[e] * sum_v Xl[v]
// ===========================================================================
__global__ __launch_bounds__(256) void gather_e_kernel(
    const bf16* __restrict__ Xl, const int* __restrict__ perm,
    const int* __restrict__ offs, const float* __restrict__ degE,
    const float* __restrict__ W_edge, bf16* __restrict__ Xe, int E) {
  const int gtid = blockIdx.x * 256 + threadIdx.x;
  const int e    = gtid >> 6;
  const int lane = gtid & 63;
  if (e >= E) return;

  const int beg = offs[e];
  const int end = offs[e + 1];
  float acc = 0.f;

  for (int base = beg; base < end; base += 64) {
    const int n = min(64, end - base);
    const int idx = (lane < n) ? perm[base + lane] : 0;
    int jj = 0;
    for (; jj + 4 <= n; jj += 4) {
      const int v0 = __shfl(idx, jj + 0, 64);
      const int v1 = __shfl(idx, jj + 1, 64);
      const int v2 = __shfl(idx, jj + 2, 64);
      const int v3 = __shfl(idx, jj + 3, 64);
      const float f0 = bf2f(Xl[(size_t)v0 * 64 + lane]);
      const float f1 = bf2f(Xl[(size_t)v1 * 64 + lane]);
      const float f2 = bf2f(Xl[(size_t)v2 * 64 + lane]);
      const float f3 = bf2f(Xl[(size_t)v3 * 64 + lane]);
      acc += (f0 + f1) + (f2 + f3);
    }
    for (; jj < n; ++jj) {
      const int v = __shfl(idx, jj, 64);
      acc += bf2f(Xl[(size_t)v * 64 + lane]);
    }
  }
  const float s = degE[e] * W_edge[e];
  Xe[(size_t)e * 64 + lane] = __float2bfloat16(acc * s);
}

// ===========================================================================
// Gather 2: one wave per node. out[v] = degV[v] * sum_e Xe[e]
// ===========================================================================
__global__ __launch_bounds__(256) void gather_v_kernel(
    const bf16* __restrict__ Xe, const int* __restrict__ perm,
    const int* __restrict__ offs, const float* __restrict__ degV,
    float* __restrict__ out, int N, int E) {
  const int gtid = blockIdx.x * 256 + threadIdx.x;
  const int v    = gtid >> 6;
  const int lane = gtid & 63;
  if (v >= N) return;

  const int beg = offs[E + v];
  const int end = offs[E + v + 1];
  float acc = 0.f;

  for (int base = beg; base < end; base += 64) {
    const int n = min(64, end - base);
    const int idx = (lane < n) ? perm[base + lane] : 0;
    int jj = 0;
    for (; jj + 4 <= n; jj += 4) {
      const int e0 = __shfl(idx, jj + 0, 64);
      const int e1 = __shfl(idx, jj + 1, 64);
      const int e2 = __shfl(idx, jj + 2, 64);
      const int e3 = __shfl(idx, jj + 3, 64);
      const float f0 = bf2f(Xe[(size_t)e0 * 64 + lane]);
      const float f1 = bf2f(Xe[(size_t)e1 * 64 + lane]);
      const float f2 = bf2f(Xe[(size_t)e2 * 64 + lane]);
      const float f3 = bf2f(Xe[(size_t)e3 * 64 + lane]);
      acc += (f0 + f1) + (f2 + f3);
    }
    for (; jj < n; ++jj) {
      const int e = __shfl(idx, jj, 64);
      acc += bf2f(Xe[(size_t)e * 64 + lane]);
    }
  }
  __builtin_nontemporal_store(acc * degV[v], &out[(size_t)v * 64 + lane]);
}

// ===========================================================================
extern "C" void kernel_launch(void* const* d_in, const int* in_sizes, int n_in,
                              void* d_out, int out_size, void* d_ws, size_t ws_size,
                              hipStream_t stream) {
  const float* X      = (const float*)d_in[0];
  const int*   vertex = (const int*)d_in[1];
  const int*   edges  = (const int*)d_in[2];
  const float* W      = (const float*)d_in[3];
  const float* degE   = (const float*)d_in[4];
  const float* degV   = (const float*)d_in[5];
  const float* W_edge = (const float*)d_in[6];
  float* out = (float*)d_out;

  const int nnz = in_sizes[1];
  const int E   = in_sizes[4];
  const int N   = in_sizes[5];
  const int M   = E + N;

  const int nEB = (E + (1 << EB_BITS) - 1) >> EB_BITS;
  const int nVB = (N + (1 << VB_BITS) - 1) >> VB_BITS;
  const int KB  = nEB + nVB;

  const int capE = (nnz / nEB) * 3 / 2 + 256;
  const int capV = (nnz / nVB) * 3 / 2 + 256;
  const size_t rec_total = (size_t)nEB * capE + (size_t)nVB * capV;

  char* p = (char*)d_ws;
  auto alloc = [&](size_t bytes) -> void* {
    void* r = (void*)p;
    p += (bytes + 255) & ~(size_t)255;
    return r;
  };
  int*  offs    = (int*)alloc((size_t)(M + 1) * 4);   // seghist -> offs (in place)
  int*  psum    = (int*)alloc(512 * 4);
  int*  pbase   = (int*)alloc(512 * 4);
  int*  gcursor = (int*)alloc(MAXBK * 4);
  int*  perm    = (int*)alloc((size_t)2 * nnz * 4);   //  8 MB
  int*  records = (int*)alloc(rec_total * 4);         // ~12.2 MB (live w/ Xl!)
  bf16* Xl      = (bf16*)alloc((size_t)N * 64 * 2);   // 12.8 MB
  bf16* Xe      = (bf16*)alloc((size_t)E * 64 * 2);   //  2.56 MB

  const int f1blocks = (nnz + F1_ITEMS - 1) / F1_ITEMS;
  const int ntiles   = (N + 63) / 64;
  const int GB       = ntiles < 512 ? ntiles : 512;
  const int nP       = (M + SCAN_CHUNK - 1) / SCAN_CHUNK;   // 118 <= 256

  hipMemsetAsync(offs, 0, (size_t)(M + 1) * 4, stream);
  init_cursor_kernel<<<1, MAXBK, 0, stream>>>(gcursor, KB, nEB, capE, capV);
  fused1_kernel<<<f1blocks + GB, 256, 0, stream>>>(
      vertex, edges, gcursor, records, offs, X, W, Xl,
      nnz, E, KB, nEB, f1blocks, N, ntiles, GB);
  scan_part_kernel<<<nP, 256, 0, stream>>>(offs, psum, M);
  scan_top_kernel<<<1, 256, 0, stream>>>(psum, pbase, offs, nP, M);
  scan_apply_kernel<<<nP, 256, 0, stream>>>(offs, pbase, M);
  fill_bucket_kernel<<<KB, 1024, 0, stream>>>(records, gcursor, offs, perm,
                                              nEB, capE, capV, E, M);
  gather_e_kernel<<<(E + 3) / 4, 256, 0, stream>>>(Xl, perm, offs, degE, W_edge, Xe, E);
  gather_v_kernel<<<(N + 3) / 4, 256, 0, stream>>>(Xe, perm, offs, degV, out, N, E);
}

// Round 7
// 127.960 us; speedup vs baseline: 7.0091x; 1.5698x over previous
//
#include <hip/hip_runtime.h>
#include <hip/hip_bf16.h>

typedef __hip_bfloat16 bf16;
__device__ __forceinline__ float bf2f(bf16 v) { return __bfloat162float(v); }

typedef __attribute__((ext_vector_type(8))) short short8;
typedef __attribute__((ext_vector_type(4))) float floatx4;

#define EB_BITS 8            // 256 edge segments per coarse bucket
#define VB_BITS 10           // 1024 vertex segments per coarse bucket
#define MAXBK   256          // coarse bucket ceiling (79+98=177 here)
#define F1_ITEMS 1024        // incidences per bucketize block (round-1 proven)
#define XS_STRIDE 136        // ushort; gemm LDS row stride

__device__ __forceinline__ int rbase(int b, int nEB, int capE, int capV) {
  return (b < nEB) ? b * capE : nEB * capE + (b - nEB) * capV;
}

// ===========================================================================
// Init per-bucket write cursors to region bases.
// ===========================================================================
__global__ void init_cursor_kernel(int* __restrict__ gcursor, int KB,
                                   int nEB, int capE, int capV) {
  const int b = threadIdx.x;
  if (b < KB) gcursor[b] = rbase(b, nEB, capE, capV);
}

// ===========================================================================
// Bucketize body (round-1 proven, NO global atomics beyond per-block
// gcursor reservations). Record formats:
//   E-side: (e_local:8  << 17) | v
//   V-side: (v_local:10 << 17) | e
// ===========================================================================
__device__ void bucketize_body(int* smem4,
    const int* __restrict__ vertex, const int* __restrict__ edges,
    int* __restrict__ gcursor, int* __restrict__ records,
    int nnz, int KB, int nEB, int bb) {
  int* cnt    = smem4;            // 256
  int* scanEx = smem4 + 256;      // 256
  int* bases  = smem4 + 512;      // 256
  int* wsum4  = smem4 + 768;      // 4
  int* staged = smem4 + 772;      // 2048
  unsigned char* sbkt = (unsigned char*)(smem4 + 772 + 2048);  // 2048 B

  const int tid  = threadIdx.x;
  const int lane = tid & 63;
  const int wid  = tid >> 6;
  const int base = bb * F1_ITEMS;
  const int iEnd = min(nnz, base + F1_ITEMS);

  cnt[tid] = 0;
  __syncthreads();

  int recs[8];
  int bks[8];
  int nmy = 0;
#pragma unroll
  for (int j = 0; j < 4; ++j) {
    const int i = base + tid + j * 256;
    if (i < iEnd) {
      const int e = __builtin_nontemporal_load(&edges[i]);
      const int v = __builtin_nontemporal_load(&vertex[i]);
      const int bkE = e >> EB_BITS;
      recs[nmy] = ((e & ((1 << EB_BITS) - 1)) << 17) | v;  bks[nmy] = bkE;  ++nmy;
      const int bkV = nEB + (v >> VB_BITS);
      recs[nmy] = ((v & ((1 << VB_BITS) - 1)) << 17) | e;  bks[nmy] = bkV;  ++nmy;
      atomicAdd(&cnt[bkE], 1);
      atomicAdd(&cnt[bkV], 1);
    }
  }
  __syncthreads();

  // Exclusive scan over 256 buckets: shfl wave-scan + 4-way cross-wave
  const int c = cnt[tid];
  int inc = c;
#pragma unroll
  for (int d = 1; d < 64; d <<= 1) {
    int t = __shfl_up(inc, d, 64);
    if (lane >= d) inc += t;
  }
  if (lane == 63) wsum4[wid] = inc;
  __syncthreads();
  if (tid < 4) {
    int wv = wsum4[tid];
#pragma unroll
    for (int d = 1; d < 4; d <<= 1) {
      int t = __shfl_up(wv, d, 64);
      if (tid >= d) wv += t;
    }
    wsum4[tid] = wv;
  }
  __syncthreads();
  const int excl = inc - c + (wid > 0 ? wsum4[wid - 1] : 0);

  if (tid < KB && c > 0) bases[tid] = atomicAdd(&gcursor[tid], c);
  scanEx[tid] = excl;
  __syncthreads();
  cnt[tid] = 0;
  __syncthreads();

  for (int r = 0; r < nmy; ++r) {
    const int b = bks[r];
    const int p = atomicAdd(&cnt[b], 1);
    const int s = scanEx[b] + p;
    staged[s] = recs[r];
    sbkt[s] = (unsigned char)b;
  }
  __syncthreads();

  const int nrec = 2 * (iEnd - base);
  for (int s = tid; s < nrec; s += 256) {
    const int b = sbkt[s];
    records[bases[b] + (s - scanEx[b])] = staged[s];
  }
}

// ===========================================================================
// GEMM body: Xl[N,64](bf16) = X[N,128] @ W[128,64]. 4 waves, 64-row tiles,
// mfma_f32_16x16x32_bf16. LDS reused: Ws first (bfrags hoisted), then Xs.
// (round-5/6 proven; verified layouts learn_hip m89/m120)
// ===========================================================================
__device__ __forceinline__ unsigned int pack_bf16x2(float lo, float hi) {
  bf16 a = __float2bfloat16(lo);
  bf16 b = __float2bfloat16(hi);
  unsigned short ua = *(unsigned short*)&a;
  unsigned short ub = *(unsigned short*)&b;
  return (unsigned int)ua | ((unsigned int)ub << 16);
}

__device__ void gemm_body(int* smem4,
    const float* __restrict__ X, const float* __restrict__ W,
    bf16* __restrict__ Xl, int Nrows, int ntiles, int gb, int GB) {
  unsigned short* S = (unsigned short*)smem4;   // Ws, then Xs (17.4 KB)

  const int tid  = threadIdx.x;
  const int wave = tid >> 6;
  const int lane = tid & 63;
  const int quad = lane >> 4;
  const int l15  = lane & 15;

  for (int i = tid; i < 8192; i += 256) {
    const int k = i >> 6, n = i & 63;
    bf16 h = __float2bfloat16(W[i]);
    S[n * XS_STRIDE + k] = *(unsigned short*)&h;
  }
  __syncthreads();

  short8 bfrag[4][4];
#pragma unroll
  for (int ct = 0; ct < 4; ++ct)
#pragma unroll
    for (int kt = 0; kt < 4; ++kt)
      bfrag[ct][kt] = *(const short8*)&S[(ct * 16 + l15) * XS_STRIDE + kt * 32 + quad * 8];
  __syncthreads();   // done with Ws; S becomes Xs

  const int r  = tid >> 2;
  const int c0 = (tid & 3) * 32;

  for (int tile = gb; tile < ntiles; tile += GB) {
    const int row0 = tile * 64;
    {
      int rr = row0 + r;
      if (rr >= Nrows) rr = Nrows - 1;
      const float* src = X + (size_t)rr * 128 + c0;
      unsigned short* dst = &S[r * XS_STRIDE + c0];
#pragma unroll
      for (int q = 0; q < 4; ++q) {
        const float4 f0 = *(const float4*)(src + q * 8);
        const float4 f1 = *(const float4*)(src + q * 8 + 4);
        uint4 o;
        o.x = pack_bf16x2(f0.x, f0.y);
        o.y = pack_bf16x2(f0.z, f0.w);
        o.z = pack_bf16x2(f1.x, f1.y);
        o.w = pack_bf16x2(f1.z, f1.w);
        *(uint4*)(dst + q * 8) = o;
      }
    }
    __syncthreads();

    const int m = wave * 16 + l15;
    short8 afrag[4];
#pragma unroll
    for (int kt = 0; kt < 4; ++kt)
      afrag[kt] = *(const short8*)&S[m * XS_STRIDE + kt * 32 + quad * 8];

    floatx4 acc[4];
#pragma unroll
    for (int ct = 0; ct < 4; ++ct) {
      acc[ct] = (floatx4){0.f, 0.f, 0.f, 0.f};
#pragma unroll
      for (int kt = 0; kt < 4; ++kt)
        acc[ct] = __builtin_amdgcn_mfma_f32_16x16x32_bf16(
            afrag[kt], bfrag[ct][kt], acc[ct], 0, 0, 0);
    }

    const int rbase_ = row0 + wave * 16 + quad * 4;
#pragma unroll
    for (int ct = 0; ct < 4; ++ct) {
      const int col = ct * 16 + l15;
#pragma unroll
      for (int reg = 0; reg < 4; ++reg) {
        const int row = rbase_ + reg;
        if (row < Nrows) Xl[(size_t)row * 64 + col] = __float2bfloat16(acc[ct][reg]);
      }
    }
    __syncthreads();
  }
}

// ===========================================================================
// K1: bucketize + gemm co-scheduled (branch uniform per block).
// records and Xl live simultaneously -> not aliased in workspace.
// ===========================================================================
__global__ __launch_bounds__(256) void fused1_kernel(
    const int* __restrict__ vertex, const int* __restrict__ edges,
    int* __restrict__ gcursor, int* __restrict__ records,
    const float* __restrict__ X, const float* __restrict__ W,
    bf16* __restrict__ Xl,
    int nnz, int KB, int nEB, int f1blocks, int Nrows, int ntiles, int GB) {
  __shared__ int smem4[4352];   // 17.4 KB, overlaid by both bodies
  if ((int)blockIdx.x < f1blocks)
    bucketize_body(smem4, vertex, edges, gcursor, records, nnz, KB, nEB, blockIdx.x);
  else
    gemm_body(smem4, X, W, Xl, Nrows, ntiles, blockIdx.x - f1blocks, GB);
}

// ===========================================================================
// K2: cross-bucket exclusive scan. Bucket totals are FREE after bucketize:
// tot[b] = gcursor[b] - rbase(b). 1 block. Also writes offs[M] sentinel.
// ===========================================================================
__global__ __launch_bounds__(256) void btot_scan_kernel(
    const int* __restrict__ gcursor, int* __restrict__ bbase,
    int* __restrict__ offs, int KB, int nEB, int capE, int capV, int M) {
  __shared__ int ws[4];
  const int tid  = threadIdx.x;
  const int lane = tid & 63;
  const int wid  = tid >> 6;
  const int tot = (tid < KB) ? (gcursor[tid] - rbase(tid, nEB, capE, capV)) : 0;
  int inc = tot;
#pragma unroll
  for (int d = 1; d < 64; d <<= 1) {
    const int t = __shfl_up(inc, d, 64);
    if (lane >= d) inc += t;
  }
  if (lane == 63) ws[wid] = inc;
  __syncthreads();
  int wbase = 0;
  for (int w = 0; w < wid; ++w) wbase += ws[w];
  if (tid < KB) bbase[tid] = wbase + inc - tot;
  if (tid == KB - 1) offs[M] = wbase + inc;   // == 2*nnz
}

// ===========================================================================
// K3: fused hist + scan + fill, one block per bucket (1024 threads).
// pass1: LDS histogram of the bucket's records (HBM read, ~46KB/bucket).
// scan:  1024-wide shfl scan -> global segment offsets (+bbase) -> offs.
// pass2: re-read records (L2-hot) and place into perm via LDS cursors.
// Replaces round-1's separate hist + scan + fill (saves one 8MB HBM pass
// over records plus two launches). LDS atomics only.
// ===========================================================================
__global__ __launch_bounds__(1024) void histfill_kernel(
    const int* __restrict__ records, const int* __restrict__ gcursor,
    const int* __restrict__ bbase, int* __restrict__ offs,
    int* __restrict__ perm, int nEB, int capE, int capV, int E, int M) {
  __shared__ int cnt[1 << VB_BITS];
  __shared__ int wsum[16];
  const int b    = blockIdx.x;
  const int tid  = threadIdx.x;
  const int lane = tid & 63;
  const int wid  = tid >> 6;

  const int base = rbase(b, nEB, capE, capV);
  const int end  = gcursor[b];
  const int bb   = bbase[b];

  cnt[tid] = 0;
  __syncthreads();

  for (int r = base + tid; r < end; r += 1024)
    atomicAdd(&cnt[records[r] >> 17], 1);
  __syncthreads();

  // 1024-wide exclusive scan (shfl wave-scan + 16-way cross-wave)
  const int c = cnt[tid];
  int inc = c;
#pragma unroll
  for (int d = 1; d < 64; d <<= 1) {
    const int t = __shfl_up(inc, d, 64);
    if (lane >= d) inc += t;
  }
  if (lane == 63) wsum[wid] = inc;
  __syncthreads();
  if (tid < 16) {
    int wv = wsum[tid];
#pragma unroll
    for (int d = 1; d < 16; d <<= 1) {
      const int t = __shfl_up(wv, d, 64);
      if (tid >= d) wv += t;
    }
    wsum[tid] = wv;
  }
  __syncthreads();
  const int goff = bb + inc - c + (wid > 0 ? wsum[wid - 1] : 0);

  int seg_lo, segN;
  if (b < nEB) { seg_lo = b << EB_BITS;               segN = min(E - seg_lo, 1 << EB_BITS); }
  else         { seg_lo = E + ((b - nEB) << VB_BITS); segN = min(M - seg_lo, 1 << VB_BITS); }
  if (tid < segN) offs[seg_lo + tid] = goff;
  // all cnt reads for the scan are done; convert to cursors
  cnt[tid] = goff;
  __syncthreads();

  for (int r = base + tid; r < end; r += 1024) {
    const int rec = records[r];
    const int p = atomicAdd(&cnt[rec >> 17], 1);
    perm[p] = rec & 0x1FFFF;
  }
}

// ===========================================================================
// Gather 1: one wave per hyperedge. Xe[e] = degE[e]*W_edge[e] * sum_v Xl[v]
// ===========================================================================
__global__ __launch_bounds__(256) void gather_e_kernel(
    const bf16* __restrict__ Xl, const int* __restrict__ perm,
    const int* __restrict__ offs, const float* __restrict__ degE,
    const float* __restrict__ W_edge, bf16* __restrict__ Xe, int E) {
  const int gtid = blockIdx.x * 256 + threadIdx.x;
  const int e    = gtid >> 6;
  const int lane = gtid & 63;
  if (e >= E) return;

  const int beg = offs[e];
  const int end = offs[e + 1];
  float acc = 0.f;

  for (int base = beg; base < end; base += 64) {
    const int n = min(64, end - base);
    const int idx = (lane < n) ? perm[base + lane] : 0;
    int jj = 0;
    for (; jj + 4 <= n; jj += 4) {
      const int v0 = __shfl(idx, jj + 0, 64);
      const int v1 = __shfl(idx, jj + 1, 64);
      const int v2 = __shfl(idx, jj + 2, 64);
      const int v3 = __shfl(idx, jj + 3, 64);
      const float f0 = bf2f(Xl[(size_t)v0 * 64 + lane]);
      const float f1 = bf2f(Xl[(size_t)v1 * 64 + lane]);
      const float f2 = bf2f(Xl[(size_t)v2 * 64 + lane]);
      const float f3 = bf2f(Xl[(size_t)v3 * 64 + lane]);
      acc += (f0 + f1) + (f2 + f3);
    }
    for (; jj < n; ++jj) {
      const int v = __shfl(idx, jj, 64);
      acc += bf2f(Xl[(size_t)v * 64 + lane]);
    }
  }
  const float s = degE[e] * W_edge[e];
  Xe[(size_t)e * 64 + lane] = __float2bfloat16(acc * s);
}

// ===========================================================================
// Gather 2: one wave per node. out[v] = degV[v] * sum_e Xe[e]
// ===========================================================================
__global__ __launch_bounds__(256) void gather_v_kernel(
    const bf16* __restrict__ Xe, const int* __restrict__ perm,
    const int* __restrict__ offs, const float* __restrict__ degV,
    float* __restrict__ out, int N, int E) {
  const int gtid = blockIdx.x * 256 + threadIdx.x;
  const int v    = gtid >> 6;
  const int lane = gtid & 63;
  if (v >= N) return;

  const int beg = offs[E + v];
  const int end = offs[E + v + 1];
  float acc = 0.f;

  for (int base = beg; base < end; base += 64) {
    const int n = min(64, end - base);
    const int idx = (lane < n) ? perm[base + lane] : 0;
    int jj = 0;
    for (; jj + 4 <= n; jj += 4) {
      const int e0 = __shfl(idx, jj + 0, 64);
      const int e1 = __shfl(idx, jj + 1, 64);
      const int e2 = __shfl(idx, jj + 2, 64);
      const int e3 = __shfl(idx, jj + 3, 64);
      const float f0 = bf2f(Xe[(size_t)e0 * 64 + lane]);
      const float f1 = bf2f(Xe[(size_t)e1 * 64 + lane]);
      const float f2 = bf2f(Xe[(size_t)e2 * 64 + lane]);
      const float f3 = bf2f(Xe[(size_t)e3 * 64 + lane]);
      acc += (f0 + f1) + (f2 + f3);
    }
    for (; jj < n; ++jj) {
      const int e = __shfl(idx, jj, 64);
      acc += bf2f(Xe[(size_t)e * 64 + lane]);
    }
  }
  __builtin_nontemporal_store(acc * degV[v], &out[(size_t)v * 64 + lane]);
}

// ===========================================================================
extern "C" void kernel_launch(void* const* d_in, const int* in_sizes, int n_in,
                              void* d_out, int out_size, void* d_ws, size_t ws_size,
                              hipStream_t stream) {
  const float* X      = (const float*)d_in[0];
  const int*   vertex = (const int*)d_in[1];
  const int*   edges  = (const int*)d_in[2];
  const float* W      = (const float*)d_in[3];
  const float* degE   = (const float*)d_in[4];
  const float* degV   = (const float*)d_in[5];
  const float* W_edge = (const float*)d_in[6];
  float* out = (float*)d_out;

  const int nnz = in_sizes[1];
  const int E   = in_sizes[4];
  const int N   = in_sizes[5];
  const int M   = E + N;

  const int nEB = (E + (1 << EB_BITS) - 1) >> EB_BITS;
  const int nVB = (N + (1 << VB_BITS) - 1) >> VB_BITS;
  const int KB  = nEB + nVB;

  const int capE = (nnz / nEB) * 3 / 2 + 256;
  const int capV = (nnz / nVB) * 3 / 2 + 256;
  const size_t rec_total = (size_t)nEB * capE + (size_t)nVB * capV;

  char* p = (char*)d_ws;
  auto alloc = [&](size_t bytes) -> void* {
    void* r = (void*)p;
    p += (bytes + 255) & ~(size_t)255;
    return r;
  };
  int*  offs    = (int*)alloc((size_t)(M + 1) * 4);
  int*  bbase   = (int*)alloc(MAXBK * 4);
  int*  gcursor = (int*)alloc(MAXBK * 4);
  int*  perm    = (int*)alloc((size_t)2 * nnz * 4);   //  8 MB
  int*  records = (int*)alloc(rec_total * 4);         // ~12.2 MB (live w/ Xl)
  bf16* Xl      = (bf16*)alloc((size_t)N * 64 * 2);   // 12.8 MB
  bf16* Xe      = (bf16*)alloc((size_t)E * 64 * 2);   //  2.56 MB

  const int f1blocks = (nnz + F1_ITEMS - 1) / F1_ITEMS;
  const int ntiles   = (N + 63) / 64;
  const int GB       = ntiles < 512 ? ntiles : 512;

  init_cursor_kernel<<<1, MAXBK, 0, stream>>>(gcursor, KB, nEB, capE, capV);
  fused1_kernel<<<f1blocks + GB, 256, 0, stream>>>(
      vertex, edges, gcursor, records, X, W, Xl,
      nnz, KB, nEB, f1blocks, N, ntiles, GB);
  btot_scan_kernel<<<1, 256, 0, stream>>>(gcursor, bbase, offs, KB, nEB, capE, capV, M);
  histfill_kernel<<<KB, 1024, 0, stream>>>(records, gcursor, bbase, offs, perm,
                                           nEB, capE, capV, E, M);
  gather_e_kernel<<<(E + 3) / 4, 256, 0, stream>>>(Xl, perm, offs, degE, W_edge, Xe, E);
  gather_v_kernel<<<(N + 3) / 4, 256, 0, stream>>>(Xe, perm, offs, degV, out, N, E);
}

// Round 8
// 121.783 us; speedup vs baseline: 7.3646x; 1.0507x over previous
//
#include <hip/hip_runtime.h>
#include <hip/hip_bf16.h>

typedef __hip_bfloat16 bf16;
__device__ __forceinline__ float bf2f(bf16 v) { return __bfloat162float(v); }

typedef __attribute__((ext_vector_type(8))) short short8;
typedef __attribute__((ext_vector_type(4))) float floatx4;

#define EB_BITS 8            // 256 edge segments per coarse bucket
#define VB_BITS 10           // 1024 vertex segments per coarse bucket
#define MAXBK   256          // coarse bucket ceiling (79+98=177 here)
#define F1_ITEMS 2048        // incidences per bucketize block (2x r7: longer
                             // record runs -> fewer partial-line RMWs; half
                             // the gcursor atomic traffic)
#define XS_STRIDE 136        // ushort; gemm LDS row stride
// shared LDS union: bucketize needs 772+4096 ints + 4096B sbkt = 23568 B
#define SMEM_INTS 5892

__device__ __forceinline__ int rbase(int b, int nEB, int capE, int capV) {
  return (b < nEB) ? b * capE : nEB * capE + (b - nEB) * capV;
}

// ===========================================================================
// Init per-bucket write cursors to region bases.
// ===========================================================================
__global__ void init_cursor_kernel(int* __restrict__ gcursor, int KB,
                                   int nEB, int capE, int capV) {
  const int b = threadIdx.x;
  if (b < KB) gcursor[b] = rbase(b, nEB, capE, capV);
}

// ===========================================================================
// Bucketize body (round-1/7 proven; only global atomics = per-block gcursor
// reservations on 177 L2-resident counters). Record formats:
//   E-side: (e_local:8  << 17) | v
//   V-side: (v_local:10 << 17) | e
// ===========================================================================
__device__ void bucketize_body(int* smem4,
    const int* __restrict__ vertex, const int* __restrict__ edges,
    int* __restrict__ gcursor, int* __restrict__ records,
    int nnz, int KB, int nEB, int bb) {
  int* cnt    = smem4;            // 256
  int* scanEx = smem4 + 256;      // 256
  int* bases  = smem4 + 512;      // 256
  int* wsum4  = smem4 + 768;      // 4
  int* staged = smem4 + 772;      // 4096
  unsigned char* sbkt = (unsigned char*)(smem4 + 772 + 4096);  // 4096 B

  const int tid  = threadIdx.x;
  const int lane = tid & 63;
  const int wid  = tid >> 6;
  const int base = bb * F1_ITEMS;
  const int iEnd = min(nnz, base + F1_ITEMS);

  cnt[tid] = 0;
  __syncthreads();

  int recs[16];
  int bks[16];
  int nmy = 0;
#pragma unroll
  for (int j = 0; j < 8; ++j) {
    const int i = base + tid + j * 256;
    if (i < iEnd) {
      const int e = __builtin_nontemporal_load(&edges[i]);
      const int v = __builtin_nontemporal_load(&vertex[i]);
      const int bkE = e >> EB_BITS;
      recs[nmy] = ((e & ((1 << EB_BITS) - 1)) << 17) | v;  bks[nmy] = bkE;  ++nmy;
      const int bkV = nEB + (v >> VB_BITS);
      recs[nmy] = ((v & ((1 << VB_BITS) - 1)) << 17) | e;  bks[nmy] = bkV;  ++nmy;
      atomicAdd(&cnt[bkE], 1);
      atomicAdd(&cnt[bkV], 1);
    }
  }
  __syncthreads();

  // Exclusive scan over 256 buckets: shfl wave-scan + 4-way cross-wave
  const int c = cnt[tid];
  int inc = c;
#pragma unroll
  for (int d = 1; d < 64; d <<= 1) {
    int t = __shfl_up(inc, d, 64);
    if (lane >= d) inc += t;
  }
  if (lane == 63) wsum4[wid] = inc;
  __syncthreads();
  if (tid < 4) {
    int wv = wsum4[tid];
#pragma unroll
    for (int d = 1; d < 4; d <<= 1) {
      int t = __shfl_up(wv, d, 64);
      if (tid >= d) wv += t;
    }
    wsum4[tid] = wv;
  }
  __syncthreads();
  const int excl = inc - c + (wid > 0 ? wsum4[wid - 1] : 0);

  if (tid < KB && c > 0) bases[tid] = atomicAdd(&gcursor[tid], c);
  scanEx[tid] = excl;
  __syncthreads();
  cnt[tid] = 0;
  __syncthreads();

  for (int r = 0; r < nmy; ++r) {
    const int b = bks[r];
    const int p = atomicAdd(&cnt[b], 1);
    const int s = scanEx[b] + p;
    staged[s] = recs[r];
    sbkt[s] = (unsigned char)b;
  }
  __syncthreads();

  const int nrec = 2 * (iEnd - base);
  for (int s = tid; s < nrec; s += 256) {
    const int b = sbkt[s];
    records[bases[b] + (s - scanEx[b])] = staged[s];
  }
}

// ===========================================================================
// GEMM body: Xl[N,64](bf16) = X[N,128] @ W[128,64]. 4 waves, 64-row tiles,
// mfma_f32_16x16x32_bf16. LDS reused: Ws first (bfrags hoisted), then Xs.
// (round-5/6/7 proven; verified layouts learn_hip m89/m120)
// ===========================================================================
__device__ __forceinline__ unsigned int pack_bf16x2(float lo, float hi) {
  bf16 a = __float2bfloat16(lo);
  bf16 b = __float2bfloat16(hi);
  unsigned short ua = *(unsigned short*)&a;
  unsigned short ub = *(unsigned short*)&b;
  return (unsigned int)ua | ((unsigned int)ub << 16);
}

__device__ void gemm_body(int* smem4,
    const float* __restrict__ X, const float* __restrict__ W,
    bf16* __restrict__ Xl, int Nrows, int ntiles, int gb, int GB) {
  unsigned short* S = (unsigned short*)smem4;   // Ws, then Xs (17.4 KB)

  const int tid  = threadIdx.x;
  const int wave = tid >> 6;
  const int lane = tid & 63;
  const int quad = lane >> 4;
  const int l15  = lane & 15;

  for (int i = tid; i < 8192; i += 256) {
    const int k = i >> 6, n = i & 63;
    bf16 h = __float2bfloat16(W[i]);
    S[n * XS_STRIDE + k] = *(unsigned short*)&h;
  }
  __syncthreads();

  short8 bfrag[4][4];
#pragma unroll
  for (int ct = 0; ct < 4; ++ct)
#pragma unroll
    for (int kt = 0; kt < 4; ++kt)
      bfrag[ct][kt] = *(const short8*)&S[(ct * 16 + l15) * XS_STRIDE + kt * 32 + quad * 8];
  __syncthreads();   // done with Ws; S becomes Xs

  const int r  = tid >> 2;
  const int c0 = (tid & 3) * 32;

  for (int tile = gb; tile < ntiles; tile += GB) {
    const int row0 = tile * 64;
    {
      int rr = row0 + r;
      if (rr >= Nrows) rr = Nrows - 1;
      const float* src = X + (size_t)rr * 128 + c0;
      unsigned short* dst = &S[r * XS_STRIDE + c0];
#pragma unroll
      for (int q = 0; q < 4; ++q) {
        const float4 f0 = *(const float4*)(src + q * 8);
        const float4 f1 = *(const float4*)(src + q * 8 + 4);
        uint4 o;
        o.x = pack_bf16x2(f0.x, f0.y);
        o.y = pack_bf16x2(f0.z, f0.w);
        o.z = pack_bf16x2(f1.x, f1.y);
        o.w = pack_bf16x2(f1.z, f1.w);
        *(uint4*)(dst + q * 8) = o;
      }
    }
    __syncthreads();

    const int m = wave * 16 + l15;
    short8 afrag[4];
#pragma unroll
    for (int kt = 0; kt < 4; ++kt)
      afrag[kt] = *(const short8*)&S[m * XS_STRIDE + kt * 32 + quad * 8];

    floatx4 acc[4];
#pragma unroll
    for (int ct = 0; ct < 4; ++ct) {
      acc[ct] = (floatx4){0.f, 0.f, 0.f, 0.f};
#pragma unroll
      for (int kt = 0; kt < 4; ++kt)
        acc[ct] = __builtin_amdgcn_mfma_f32_16x16x32_bf16(
            afrag[kt], bfrag[ct][kt], acc[ct], 0, 0, 0);
    }

    const int rbase_ = row0 + wave * 16 + quad * 4;
#pragma unroll
    for (int ct = 0; ct < 4; ++ct) {
      const int col = ct * 16 + l15;
#pragma unroll
      for (int reg = 0; reg < 4; ++reg) {
        const int row = rbase_ + reg;
        if (row < Nrows) Xl[(size_t)row * 64 + col] = __float2bfloat16(acc[ct][reg]);
      }
    }
    __syncthreads();
  }
}

// ===========================================================================
// K1: GEMM FIRST (resident immediately, long-running), bucketize fills the
// remaining CU capacity concurrently -> true overlap (r7 ran them serially:
// occupancy profile showed a 2-block/CU gemm tail).
// ===========================================================================
__global__ __launch_bounds__(256) void fused1_kernel(
    const int* __restrict__ vertex, const int* __restrict__ edges,
    int* __restrict__ gcursor, int* __restrict__ records,
    const float* __restrict__ X, const float* __restrict__ W,
    bf16* __restrict__ Xl,
    int nnz, int KB, int nEB, int Nrows, int ntiles, int GB) {
  __shared__ int smem4[SMEM_INTS];   // 23.6 KB union
  if ((int)blockIdx.x < GB)
    gemm_body(smem4, X, W, Xl, Nrows, ntiles, blockIdx.x, GB);
  else
    bucketize_body(smem4, vertex, edges, gcursor, records, nnz, KB, nEB,
                   blockIdx.x - GB);
}

// ===========================================================================
// K2: fused cross-bucket scan + hist + seg-scan + fill (1024 thr/bucket).
// Bucket totals are free: tot[b] = gcursor[b]-rbase(b); each block scans the
// 177 totals itself (~300 cyc) -> btot_scan kernel deleted.
// pass1: LDS histogram of the bucket's records; 1024-wide scan -> offs.
// pass2: re-read records (L2-hot), place into perm via LDS cursors.
// LDS atomics only.
// ===========================================================================
__global__ __launch_bounds__(1024) void histfill_kernel(
    const int* __restrict__ records, const int* __restrict__ gcursor,
    int* __restrict__ offs, int* __restrict__ perm,
    int nEB, int capE, int capV, int E, int M, int KB, int totrec) {
  __shared__ int cnt[1 << VB_BITS];
  __shared__ int wsum[16];
  const int b    = blockIdx.x;
  const int tid  = threadIdx.x;
  const int lane = tid & 63;
  const int wid  = tid >> 6;

  const int base = rbase(b, nEB, capE, capV);
  const int end  = gcursor[b];

  // ---- inline cross-bucket exclusive scan (first 4 waves) ----
  int bb = 0;
  {
    const int tot = (tid < KB) ? (gcursor[tid] - rbase(tid, nEB, capE, capV)) : 0;
    int inc = tot;
    if (tid < 256) {
#pragma unroll
      for (int d = 1; d < 64; d <<= 1) {
        const int t = __shfl_up(inc, d, 64);
        if (lane >= d) inc += t;
      }
      if (lane == 63) wsum[wid] = inc;
    }
    __syncthreads();
    if (tid < 256) {
      int wbase = 0;
      for (int w = 0; w < wid; ++w) wbase += wsum[w];
      cnt[tid] = wbase + inc - tot;
    }
    __syncthreads();
    bb = cnt[b];
    __syncthreads();
  }
  if (b == 0 && tid == 0) offs[M] = totrec;   // sentinel = 2*nnz

  cnt[tid] = 0;
  __syncthreads();

  for (int r = base + tid; r < end; r += 1024)
    atomicAdd(&cnt[records[r] >> 17], 1);
  __syncthreads();

  // 1024-wide exclusive scan (shfl wave-scan + 16-way cross-wave)
  const int c = cnt[tid];
  int inc = c;
#pragma unroll
  for (int d = 1; d < 64; d <<= 1) {
    const int t = __shfl_up(inc, d, 64);
    if (lane >= d) inc += t;
  }
  if (lane == 63) wsum[wid] = inc;
  __syncthreads();
  if (tid < 16) {
    int wv = wsum[tid];
#pragma unroll
    for (int d = 1; d < 16; d <<= 1) {
      const int t = __shfl_up(wv, d, 64);
      if (tid >= d) wv += t;
    }
    wsum[tid] = wv;
  }
  __syncthreads();
  const int goff = bb + inc - c + (wid > 0 ? wsum[wid - 1] : 0);

  int seg_lo, segN;
  if (b < nEB) { seg_lo = b << EB_BITS;               segN = min(E - seg_lo, 1 << EB_BITS); }
  else         { seg_lo = E + ((b - nEB) << VB_BITS); segN = min(M - seg_lo, 1 << VB_BITS); }
  if (tid < segN) offs[seg_lo + tid] = goff;
  // all cnt reads for the scan are done; convert to cursors
  cnt[tid] = goff;
  __syncthreads();

  for (int r = base + tid; r < end; r += 1024) {
    const int rec = records[r];
    const int p = atomicAdd(&cnt[rec >> 17], 1);
    perm[p] = rec & 0x1FFFF;
  }
}

// ===========================================================================
// Gather 1: one wave per hyperedge. Xe[e] = degE[e]*W_edge[e] * sum_v Xl[v]
// ===========================================================================
__global__ __launch_bounds__(256) void gather_e_kernel(
    const bf16* __restrict__ Xl, const int* __restrict__ perm,
    const int* __restrict__ offs, const float* __restrict__ degE,
    const float* __restrict__ W_edge, bf16* __restrict__ Xe, int E) {
  const int gtid = blockIdx.x * 256 + threadIdx.x;
  const int e    = gtid >> 6;
  const int lane = gtid & 63;
  if (e >= E) return;

  const int beg = offs[e];
  const int end = offs[e + 1];
  float acc = 0.f;

  for (int base = beg; base < end; base += 64) {
    const int n = min(64, end - base);
    const int idx = (lane < n) ? perm[base + lane] : 0;
    int jj = 0;
    for (; jj + 4 <= n; jj += 4) {
      const int v0 = __shfl(idx, jj + 0, 64);
      const int v1 = __shfl(idx, jj + 1, 64);
      const int v2 = __shfl(idx, jj + 2, 64);
      const int v3 = __shfl(idx, jj + 3, 64);
      const float f0 = bf2f(Xl[(size_t)v0 * 64 + lane]);
      const float f1 = bf2f(Xl[(size_t)v1 * 64 + lane]);
      const float f2 = bf2f(Xl[(size_t)v2 * 64 + lane]);
      const float f3 = bf2f(Xl[(size_t)v3 * 64 + lane]);
      acc += (f0 + f1) + (f2 + f3);
    }
    for (; jj < n; ++jj) {
      const int v = __shfl(idx, jj, 64);
      acc += bf2f(Xl[(size_t)v * 64 + lane]);
    }
  }
  const float s = degE[e] * W_edge[e];
  Xe[(size_t)e * 64 + lane] = __float2bfloat16(acc * s);
}

// ===========================================================================
// Gather 2: one wave per node. out[v] = degV[v] * sum_e Xe[e]
// ===========================================================================
__global__ __launch_bounds__(256) void gather_v_kernel(
    const bf16* __restrict__ Xe, const int* __restrict__ perm,
    const int* __restrict__ offs, const float* __restrict__ degV,
    float* __restrict__ out, int N, int E) {
  const int gtid = blockIdx.x * 256 + threadIdx.x;
  const int v    = gtid >> 6;
  const int lane = gtid & 63;
  if (v >= N) return;

  const int beg = offs[E + v];
  const int end = offs[E + v + 1];
  float acc = 0.f;

  for (int base = beg; base < end; base += 64) {
    const int n = min(64, end - base);
    const int idx = (lane < n) ? perm[base + lane] : 0;
    int jj = 0;
    for (; jj + 4 <= n; jj += 4) {
      const int e0 = __shfl(idx, jj + 0, 64);
      const int e1 = __shfl(idx, jj + 1, 64);
      const int e2 = __shfl(idx, jj + 2, 64);
      const int e3 = __shfl(idx, jj + 3, 64);
      const float f0 = bf2f(Xe[(size_t)e0 * 64 + lane]);
      const float f1 = bf2f(Xe[(size_t)e1 * 64 + lane]);
      const float f2 = bf2f(Xe[(size_t)e2 * 64 + lane]);
      const float f3 = bf2f(Xe[(size_t)e3 * 64 + lane]);
      acc += (f0 + f1) + (f2 + f3);
    }
    for (; jj < n; ++jj) {
      const int e = __shfl(idx, jj, 64);
      acc += bf2f(Xe[(size_t)e * 64 + lane]);
    }
  }
  __builtin_nontemporal_store(acc * degV[v], &out[(size_t)v * 64 + lane]);
}

// ===========================================================================
extern "C" void kernel_launch(void* const* d_in, const int* in_sizes, int n_in,
                              void* d_out, int out_size, void* d_ws, size_t ws_size,
                              hipStream_t stream) {
  const float* X      = (const float*)d_in[0];
  const int*   vertex = (const int*)d_in[1];
  const int*   edges  = (const int*)d_in[2];
  const float* W      = (const float*)d_in[3];
  const float* degE   = (const float*)d_in[4];
  const float* degV   = (const float*)d_in[5];
  const float* W_edge = (const float*)d_in[6];
  float* out = (float*)d_out;

  const int nnz = in_sizes[1];
  const int E   = in_sizes[4];
  const int N   = in_sizes[5];
  const int M   = E + N;

  const int nEB = (E + (1 << EB_BITS) - 1) >> EB_BITS;
  const int nVB = (N + (1 << VB_BITS) - 1) >> VB_BITS;
  const int KB  = nEB + nVB;

  const int capE = (nnz / nEB) * 3 / 2 + 256;
  const int capV = (nnz / nVB) * 3 / 2 + 256;
  const size_t rec_total = (size_t)nEB * capE + (size_t)nVB * capV;

  char* p = (char*)d_ws;
  auto alloc = [&](size_t bytes) -> void* {
    void* r = (void*)p;
    p += (bytes + 255) & ~(size_t)255;
    return r;
  };
  int*  offs    = (int*)alloc((size_t)(M + 1) * 4);
  int*  gcursor = (int*)alloc(MAXBK * 4);
  int*  perm    = (int*)alloc((size_t)2 * nnz * 4);   //  8 MB
  int*  records = (int*)alloc(rec_total * 4);         // ~12.2 MB (live w/ Xl)
  bf16* Xl      = (bf16*)alloc((size_t)N * 64 * 2);   // 12.8 MB
  bf16* Xe      = (bf16*)alloc((size_t)E * 64 * 2);   //  2.56 MB

  const int f1blocks = (nnz + F1_ITEMS - 1) / F1_ITEMS;
  const int ntiles   = (N + 63) / 64;
  const int GB       = ntiles < 512 ? ntiles : 512;

  init_cursor_kernel<<<1, MAXBK, 0, stream>>>(gcursor, KB, nEB, capE, capV);
  fused1_kernel<<<GB + f1blocks, 256, 0, stream>>>(
      vertex, edges, gcursor, records, X, W, Xl,
      nnz, KB, nEB, N, ntiles, GB);
  histfill_kernel<<<KB, 1024, 0, stream>>>(records, gcursor, offs, perm,
                                           nEB, capE, capV, E, M, KB, 2 * nnz);
  gather_e_kernel<<<(E + 3) / 4, 256, 0, stream>>>(Xl, perm, offs, degE, W_edge, Xe, E);
  gather_v_kernel<<<(N + 3) / 4, 256, 0, stream>>>(Xe, perm, offs, degV, out, N, E);
}

// Round 9
// 113.660 us; speedup vs baseline: 7.8910x; 1.0715x over previous
//
#include <hip/hip_runtime.h>
#include <hip/hip_bf16.h>

typedef __hip_bfloat16 bf16;
__device__ __forceinline__ float bf2f(bf16 v) { return __bfloat162float(v); }

typedef __attribute__((ext_vector_type(8))) short short8;
typedef __attribute__((ext_vector_type(4))) float floatx4;

#define EB_BITS 8            // 256 edge segments per coarse bucket
#define VB_BITS 10           // 1024 vertex segments per coarse bucket
#define MAXBK   256          // coarse bucket ceiling (79+98=177 here)
#define F1_ITEMS 2048        // incidences per bucketize block
#define XS_STRIDE 136        // ushort; gemm LDS row stride
#define SMEM_INTS 5892       // 23.6 KB union (bucketize needs 772+4096 ints + 4096B)
#define HF_MAXIT 20          // histfill: max 20*1024 records/bucket (capE~19.2k ok)

__device__ __forceinline__ int rbase(int b, int nEB, int capE, int capV) {
  return (b < nEB) ? b * capE : nEB * capE + (b - nEB) * capV;
}

// ===========================================================================
// Init per-bucket write cursors to region bases.
// ===========================================================================
__global__ void init_cursor_kernel(int* __restrict__ gcursor, int KB,
                                   int nEB, int capE, int capV) {
  const int b = threadIdx.x;
  if (b < KB) gcursor[b] = rbase(b, nEB, capE, capV);
}

// ===========================================================================
// Bucketize body — reservation-style: ONE LDS atomic per record (reservation
// p saved in registers at histogram time); placement after the scan is a
// plain store at scanEx[bk]+p. Register arrays statically indexed (no scratch).
// Record formats:  E: (e_local:8 <<17)|v   V: (v_local:10 <<17)|e
// ===========================================================================
__device__ void bucketize_body(int* smem4,
    const int* __restrict__ vertex, const int* __restrict__ edges,
    int* __restrict__ gcursor, int* __restrict__ records,
    int nnz, int KB, int nEB, int bb) {
  int* cnt    = smem4;            // 256
  int* scanEx = smem4 + 256;      // 256
  int* bases  = smem4 + 512;      // 256
  int* wsum4  = smem4 + 768;      // 4
  int* staged = smem4 + 772;      // 4096
  unsigned char* sbkt = (unsigned char*)(smem4 + 772 + 4096);  // 4096 B

  const int tid  = threadIdx.x;
  const int lane = tid & 63;
  const int wid  = tid >> 6;
  const int base = bb * F1_ITEMS;
  const int iEnd = min(nnz, base + F1_ITEMS);

  cnt[tid] = 0;
  __syncthreads();

  int recs[16], bks[16], ps[16];
#pragma unroll
  for (int j = 0; j < 8; ++j) {
    const int i = base + tid + j * 256;
    if (i < iEnd) {
      const int e = __builtin_nontemporal_load(&edges[i]);
      const int v = __builtin_nontemporal_load(&vertex[i]);
      const int bkE = e >> EB_BITS;
      const int bkV = nEB + (v >> VB_BITS);
      recs[2*j]   = ((e & ((1 << EB_BITS) - 1)) << 17) | v;
      bks[2*j]    = bkE;
      ps[2*j]     = atomicAdd(&cnt[bkE], 1);
      recs[2*j+1] = ((v & ((1 << VB_BITS) - 1)) << 17) | e;
      bks[2*j+1]  = bkV;
      ps[2*j+1]   = atomicAdd(&cnt[bkV], 1);
    } else {
      bks[2*j] = -1;  bks[2*j+1] = -1;
    }
  }
  __syncthreads();

  // Exclusive scan over 256 buckets: shfl wave-scan + 4-way cross-wave
  const int c = cnt[tid];
  int inc = c;
#pragma unroll
  for (int d = 1; d < 64; d <<= 1) {
    int t = __shfl_up(inc, d, 64);
    if (lane >= d) inc += t;
  }
  if (lane == 63) wsum4[wid] = inc;
  __syncthreads();
  if (tid < 4) {
    int wv = wsum4[tid];
#pragma unroll
    for (int d = 1; d < 4; d <<= 1) {
      int t = __shfl_up(wv, d, 64);
      if (tid >= d) wv += t;
    }
    wsum4[tid] = wv;
  }
  __syncthreads();
  const int excl = inc - c + (wid > 0 ? wsum4[wid - 1] : 0);

  if (tid < KB && c > 0) bases[tid] = atomicAdd(&gcursor[tid], c);
  scanEx[tid] = excl;
  __syncthreads();

  // Placement: plain LDS stores (reservation already holds the slot)
#pragma unroll
  for (int j = 0; j < 16; ++j) {
    if (bks[j] >= 0) {
      const int s = scanEx[bks[j]] + ps[j];
      staged[s] = recs[j];
      sbkt[s] = (unsigned char)bks[j];
    }
  }
  __syncthreads();

  const int nrec = 2 * (iEnd - base);
  for (int s = tid; s < nrec; s += 256) {
    const int b = sbkt[s];
    records[bases[b] + (s - scanEx[b])] = staged[s];
  }
}

// ===========================================================================
// GEMM body: Xl[N,64](bf16) = X[N,128] @ W[128,64]. 4 waves, 64-row tiles,
// mfma_f32_16x16x32_bf16. LDS reused: Ws first (bfrags hoisted), then Xs.
// (round-5/6/7/8 proven; verified layouts learn_hip m89/m120)
// ===========================================================================
__device__ __forceinline__ unsigned int pack_bf16x2(float lo, float hi) {
  bf16 a = __float2bfloat16(lo);
  bf16 b = __float2bfloat16(hi);
  unsigned short ua = *(unsigned short*)&a;
  unsigned short ub = *(unsigned short*)&b;
  return (unsigned int)ua | ((unsigned int)ub << 16);
}

__device__ void gemm_body(int* smem4,
    const float* __restrict__ X, const float* __restrict__ W,
    bf16* __restrict__ Xl, int Nrows, int ntiles, int gb, int GB) {
  unsigned short* S = (unsigned short*)smem4;   // Ws, then Xs (17.4 KB)

  const int tid  = threadIdx.x;
  const int wave = tid >> 6;
  const int lane = tid & 63;
  const int quad = lane >> 4;
  const int l15  = lane & 15;

  for (int i = tid; i < 8192; i += 256) {
    const int k = i >> 6, n = i & 63;
    bf16 h = __float2bfloat16(W[i]);
    S[n * XS_STRIDE + k] = *(unsigned short*)&h;
  }
  __syncthreads();

  short8 bfrag[4][4];
#pragma unroll
  for (int ct = 0; ct < 4; ++ct)
#pragma unroll
    for (int kt = 0; kt < 4; ++kt)
      bfrag[ct][kt] = *(const short8*)&S[(ct * 16 + l15) * XS_STRIDE + kt * 32 + quad * 8];
  __syncthreads();   // done with Ws; S becomes Xs

  const int r  = tid >> 2;
  const int c0 = (tid & 3) * 32;

  for (int tile = gb; tile < ntiles; tile += GB) {
    const int row0 = tile * 64;
    {
      int rr = row0 + r;
      if (rr >= Nrows) rr = Nrows - 1;
      const float* src = X + (size_t)rr * 128 + c0;
      unsigned short* dst = &S[r * XS_STRIDE + c0];
#pragma unroll
      for (int q = 0; q < 4; ++q) {
        const float4 f0 = *(const float4*)(src + q * 8);
        const float4 f1 = *(const float4*)(src + q * 8 + 4);
        uint4 o;
        o.x = pack_bf16x2(f0.x, f0.y);
        o.y = pack_bf16x2(f0.z, f0.w);
        o.z = pack_bf16x2(f1.x, f1.y);
        o.w = pack_bf16x2(f1.z, f1.w);
        *(uint4*)(dst + q * 8) = o;
      }
    }
    __syncthreads();

    const int m = wave * 16 + l15;
    short8 afrag[4];
#pragma unroll
    for (int kt = 0; kt < 4; ++kt)
      afrag[kt] = *(const short8*)&S[m * XS_STRIDE + kt * 32 + quad * 8];

    floatx4 acc[4];
#pragma unroll
    for (int ct = 0; ct < 4; ++ct) {
      acc[ct] = (floatx4){0.f, 0.f, 0.f, 0.f};
#pragma unroll
      for (int kt = 0; kt < 4; ++kt)
        acc[ct] = __builtin_amdgcn_mfma_f32_16x16x32_bf16(
            afrag[kt], bfrag[ct][kt], acc[ct], 0, 0, 0);
    }

    const int rbase_ = row0 + wave * 16 + quad * 4;
#pragma unroll
    for (int ct = 0; ct < 4; ++ct) {
      const int col = ct * 16 + l15;
#pragma unroll
      for (int reg = 0; reg < 4; ++reg) {
        const int row = rbase_ + reg;
        if (row < Nrows) Xl[(size_t)row * 64 + col] = __float2bfloat16(acc[ct][reg]);
      }
    }
    __syncthreads();
  }
}

// ===========================================================================
// K1: GEMM first, bucketize fills remaining CU capacity.
// ===========================================================================
__global__ __launch_bounds__(256) void fused1_kernel(
    const int* __restrict__ vertex, const int* __restrict__ edges,
    int* __restrict__ gcursor, int* __restrict__ records,
    const float* __restrict__ X, const float* __restrict__ W,
    bf16* __restrict__ Xl,
    int nnz, int KB, int nEB, int Nrows, int ntiles, int GB) {
  __shared__ int smem4[SMEM_INTS];   // 23.6 KB union
  if ((int)blockIdx.x < GB)
    gemm_body(smem4, X, W, Xl, Nrows, ntiles, blockIdx.x, GB);
  else
    bucketize_body(smem4, vertex, edges, gcursor, records, nnz, KB, nEB,
                   blockIdx.x - GB);
}

// ===========================================================================
// K2: fused cross-bucket scan + hist + seg-scan + fill, reservation-style:
// pass1 reads each record ONCE (nontemporal), reserves p in registers;
// pass2 is plain global stores at offs[seg]+p. No second records read,
// half the LDS atomics. Register arrays statically indexed.
// ===========================================================================
__global__ __launch_bounds__(1024) void histfill_kernel(
    const int* __restrict__ records, const int* __restrict__ gcursor,
    int* __restrict__ offs, int* __restrict__ perm,
    int nEB, int capE, int capV, int E, int M, int KB, int totrec) {
  __shared__ int cnt[1 << VB_BITS];
  __shared__ int wsum[16];
  const int b    = blockIdx.x;
  const int tid  = threadIdx.x;
  const int lane = tid & 63;
  const int wid  = tid >> 6;

  const int base = rbase(b, nEB, capE, capV);
  const int end  = gcursor[b];

  // ---- inline cross-bucket exclusive scan (first 4 waves) ----
  int bb = 0;
  {
    const int tot = (tid < KB) ? (gcursor[tid] - rbase(tid, nEB, capE, capV)) : 0;
    int inc = tot;
    if (tid < 256) {
#pragma unroll
      for (int d = 1; d < 64; d <<= 1) {
        const int t = __shfl_up(inc, d, 64);
        if (lane >= d) inc += t;
      }
      if (lane == 63) wsum[wid] = inc;
    }
    __syncthreads();
    if (tid < 256) {
      int wbase = 0;
      for (int w = 0; w < wid; ++w) wbase += wsum[w];
      cnt[tid] = wbase + inc - tot;
    }
    __syncthreads();
    bb = cnt[b];
    __syncthreads();
  }
  if (b == 0 && tid == 0) offs[M] = totrec;   // sentinel = 2*nnz

  cnt[tid] = 0;
  __syncthreads();

  // pass1: read + reserve (records read ONCE; capE/capV <= HF_MAXIT*1024)
  int myrec[HF_MAXIT], myp[HF_MAXIT];
#pragma unroll
  for (int it = 0; it < HF_MAXIT; ++it) {
    const int r = base + tid + it * 1024;
    if (r < end) {
      const int rec = __builtin_nontemporal_load(&records[r]);
      myrec[it] = rec;
      myp[it] = atomicAdd(&cnt[rec >> 17], 1);
    } else {
      myrec[it] = -1;
    }
  }
  __syncthreads();

  // 1024-wide exclusive scan (shfl wave-scan + 16-way cross-wave)
  const int c = cnt[tid];
  int inc = c;
#pragma unroll
  for (int d = 1; d < 64; d <<= 1) {
    const int t = __shfl_up(inc, d, 64);
    if (lane >= d) inc += t;
  }
  if (lane == 63) wsum[wid] = inc;
  __syncthreads();
  if (tid < 16) {
    int wv = wsum[tid];
#pragma unroll
    for (int d = 1; d < 16; d <<= 1) {
      const int t = __shfl_up(wv, d, 64);
      if (tid >= d) wv += t;
    }
    wsum[tid] = wv;
  }
  __syncthreads();
  const int goff = bb + inc - c + (wid > 0 ? wsum[wid - 1] : 0);

  int seg_lo, segN;
  if (b < nEB) { seg_lo = b << EB_BITS;               segN = min(E - seg_lo, 1 << EB_BITS); }
  else         { seg_lo = E + ((b - nEB) << VB_BITS); segN = min(M - seg_lo, 1 << VB_BITS); }
  if (tid < segN) offs[seg_lo + tid] = goff;
  cnt[tid] = goff;   // exclusive bases (plain reads in pass2)
  __syncthreads();

  // pass2: plain stores
#pragma unroll
  for (int it = 0; it < HF_MAXIT; ++it) {
    if (myrec[it] >= 0)
      perm[cnt[myrec[it] >> 17] + myp[it]] = myrec[it] & 0x1FFFF;
  }
}

// ===========================================================================
// Gather 1: one wave per hyperedge. Xe[e] = degE[e]*W_edge[e] * sum_v Xl[v]
// ===========================================================================
__global__ __launch_bounds__(256) void gather_e_kernel(
    const bf16* __restrict__ Xl, const int* __restrict__ perm,
    const int* __restrict__ offs, const float* __restrict__ degE,
    const float* __restrict__ W_edge, bf16* __restrict__ Xe, int E) {
  const int gtid = blockIdx.x * 256 + threadIdx.x;
  const int e    = gtid >> 6;
  const int lane = gtid & 63;
  if (e >= E) return;

  const int beg = offs[e];
  const int end = offs[e + 1];
  float acc = 0.f;

  for (int base = beg; base < end; base += 64) {
    const int n = min(64, end - base);
    const int idx = (lane < n) ? perm[base + lane] : 0;
    int jj = 0;
    for (; jj + 4 <= n; jj += 4) {
      const int v0 = __shfl(idx, jj + 0, 64);
      const int v1 = __shfl(idx, jj + 1, 64);
      const int v2 = __shfl(idx, jj + 2, 64);
      const int v3 = __shfl(idx, jj + 3, 64);
      const float f0 = bf2f(Xl[(size_t)v0 * 64 + lane]);
      const float f1 = bf2f(Xl[(size_t)v1 * 64 + lane]);
      const float f2 = bf2f(Xl[(size_t)v2 * 64 + lane]);
      const float f3 = bf2f(Xl[(size_t)v3 * 64 + lane]);
      acc += (f0 + f1) + (f2 + f3);
    }
    for (; jj < n; ++jj) {
      const int v = __shfl(idx, jj, 64);
      acc += bf2f(Xl[(size_t)v * 64 + lane]);
    }
  }
  const float s = degE[e] * W_edge[e];
  Xe[(size_t)e * 64 + lane] = __float2bfloat16(acc * s);
}

// ===========================================================================
// Gather 2: one wave per node. out[v] = degV[v] * sum_e Xe[e]
// ===========================================================================
__global__ __launch_bounds__(256) void gather_v_kernel(
    const bf16* __restrict__ Xe, const int* __restrict__ perm,
    const int* __restrict__ offs, const float* __restrict__ degV,
    float* __restrict__ out, int N, int E) {
  const int gtid = blockIdx.x * 256 + threadIdx.x;
  const int v    = gtid >> 6;
  const int lane = gtid & 63;
  if (v >= N) return;

  const int beg = offs[E + v];
  const int end = offs[E + v + 1];
  float acc = 0.f;

  for (int base = beg; base < end; base += 64) {
    const int n = min(64, end - base);
    const int idx = (lane < n) ? perm[base + lane] : 0;
    int jj = 0;
    for (; jj + 4 <= n; jj += 4) {
      const int e0 = __shfl(idx, jj + 0, 64);
      const int e1 = __shfl(idx, jj + 1, 64);
      const int e2 = __shfl(idx, jj + 2, 64);
      const int e3 = __shfl(idx, jj + 3, 64);
      const float f0 = bf2f(Xe[(size_t)e0 * 64 + lane]);
      const float f1 = bf2f(Xe[(size_t)e1 * 64 + lane]);
      const float f2 = bf2f(Xe[(size_t)e2 * 64 + lane]);
      const float f3 = bf2f(Xe[(size_t)e3 * 64 + lane]);
      acc += (f0 + f1) + (f2 + f3);
    }
    for (; jj < n; ++jj) {
      const int e = __shfl(idx, jj, 64);
      acc += bf2f(Xe[(size_t)e * 64 + lane]);
    }
  }
  __builtin_nontemporal_store(acc * degV[v], &out[(size_t)v * 64 + lane]);
}

// ===========================================================================
extern "C" void kernel_launch(void* const* d_in, const int* in_sizes, int n_in,
                              void* d_out, int out_size, void* d_ws, size_t ws_size,
                              hipStream_t stream) {
  const float* X      = (const float*)d_in[0];
  const int*   vertex = (const int*)d_in[1];
  const int*   edges  = (const int*)d_in[2];
  const float* W      = (const float*)d_in[3];
  const float* degE   = (const float*)d_in[4];
  const float* degV   = (const float*)d_in[5];
  const float* W_edge = (const float*)d_in[6];
  float* out = (float*)d_out;

  const int nnz = in_sizes[1];
  const int E   = in_sizes[4];
  const int N   = in_sizes[5];
  const int M   = E + N;

  const int nEB = (E + (1 << EB_BITS) - 1) >> EB_BITS;
  const int nVB = (N + (1 << VB_BITS) - 1) >> VB_BITS;
  const int KB  = nEB + nVB;

  // caps must stay <= HF_MAXIT*1024 (histfill register carry)
  int capE = (nnz / nEB) * 3 / 2 + 256;
  int capV = (nnz / nVB) * 3 / 2 + 256;
  if (capE > HF_MAXIT * 1024) capE = HF_MAXIT * 1024;
  if (capV > HF_MAXIT * 1024) capV = HF_MAXIT * 1024;
  const size_t rec_total = (size_t)nEB * capE + (size_t)nVB * capV;

  char* p = (char*)d_ws;
  auto alloc = [&](size_t bytes) -> void* {
    void* r = (void*)p;
    p += (bytes + 255) & ~(size_t)255;
    return r;
  };
  int*  offs    = (int*)alloc((size_t)(M + 1) * 4);
  int*  gcursor = (int*)alloc(MAXBK * 4);
  int*  perm    = (int*)alloc((size_t)2 * nnz * 4);   //  8 MB
  int*  records = (int*)alloc(rec_total * 4);         // ~12.2 MB (live w/ Xl)
  bf16* Xl      = (bf16*)alloc((size_t)N * 64 * 2);   // 12.8 MB
  bf16* Xe      = (bf16*)alloc((size_t)E * 64 * 2);   //  2.56 MB

  const int f1blocks = (nnz + F1_ITEMS - 1) / F1_ITEMS;
  const int ntiles   = (N + 63) / 64;
  const int GB       = ntiles < 512 ? ntiles : 512;

  init_cursor_kernel<<<1, MAXBK, 0, stream>>>(gcursor, KB, nEB, capE, capV);
  fused1_kernel<<<GB + f1blocks, 256, 0, stream>>>(
      vertex, edges, gcursor, records, X, W, Xl,
      nnz, KB, nEB, N, ntiles, GB);
  histfill_kernel<<<KB, 1024, 0, stream>>>(records, gcursor, offs, perm,
                                           nEB, capE, capV, E, M, KB, 2 * nnz);
  gather_e_kernel<<<(E + 3) / 4, 256, 0, stream>>>(Xl, perm, offs, degE, W_edge, Xe, E);
  gather_v_kernel<<<(N + 3) / 4, 256, 0, stream>>>(Xe, perm, offs, degV, out, N, E);
}